// Round 1
// baseline (417.842 us; speedup 1.0000x reference)
//
#include <hip/hip_runtime.h>
#include <hip/hip_bf16.h>
#include <math.h>

#define NB      64      // batch
#define NNODES  1023    // 2*512-1
#define LC      20      // L*C = 5*4
#define DIN     512
#define ET_PAD  404     // 400 + 4: bank-quad spread for b128 LDS reads

// ---------------------------------------------------------------------------
// prep: ET[q][i*20+j] = exp(trans[lp,ll,lr,cp,cl,cr]), Wt[q][k] = W[k][q]
//   q = lp*4+cp, i = ll*4+cl, j = lr*4+cr
// ---------------------------------------------------------------------------
__global__ __launch_bounds__(256) void prep_kernel(
    const float* __restrict__ trans, const float* __restrict__ W,
    float* __restrict__ ET, float* __restrict__ Wt)
{
    int t = blockIdx.x * 256 + threadIdx.x;
    if (t < 8000) {
        int q   = t % 20;
        int rem = t / 20;
        int j   = rem % 20;
        int i   = rem / 20;
        int ll = i >> 2, cl = i & 3;
        int lr = j >> 2, cr = j & 3;
        int lp = q >> 2, cp = q & 3;
        int src = ((((lp * 5 + ll) * 5 + lr) * 4 + cp) * 4 + cl) * 4 + cr;
        ET[q * ET_PAD + i * 20 + j] = expf(trans[src]);
    }
    if (t < LC * DIN) {
        int q = t / DIN;
        int k = t - q * DIN;
        Wt[t] = W[k * LC + q];  // Wt[q*512 + k]
    }
}

// ---------------------------------------------------------------------------
// gemm: buf[row][q] = dot(h[row,:], W[:,q]) + b[q]   (row = b*1023 + node)
// thread = (row, q); Wt rows contiguous per thread; h shared by 20 threads.
// ---------------------------------------------------------------------------
__global__ __launch_bounds__(256) void gemm_kernel(
    const float* __restrict__ h, const float* __restrict__ Wt,
    const float* __restrict__ bias, float* __restrict__ buf)
{
    int t = blockIdx.x * 256 + threadIdx.x;
    int row = t / 20;
    int q   = t - row * 20;
    if (row >= NB * NNODES) return;
    const float4* h4 = (const float4*)h  + (size_t)row * (DIN / 4);
    const float4* w4 = (const float4*)Wt + (size_t)q   * (DIN / 4);
    float a0 = 0.f, a1 = 0.f, a2 = 0.f, a3 = 0.f;
    #pragma unroll 2
    for (int k = 0; k < DIN / 4; k += 4) {
        float4 x0 = h4[k + 0], y0 = w4[k + 0];
        float4 x1 = h4[k + 1], y1 = w4[k + 1];
        float4 x2 = h4[k + 2], y2 = w4[k + 2];
        float4 x3 = h4[k + 3], y3 = w4[k + 3];
        a0 = fmaf(x0.x, y0.x, a0); a0 = fmaf(x0.y, y0.y, a0);
        a0 = fmaf(x0.z, y0.z, a0); a0 = fmaf(x0.w, y0.w, a0);
        a1 = fmaf(x1.x, y1.x, a1); a1 = fmaf(x1.y, y1.y, a1);
        a1 = fmaf(x1.z, y1.z, a1); a1 = fmaf(x1.w, y1.w, a1);
        a2 = fmaf(x2.x, y2.x, a2); a2 = fmaf(x2.y, y2.y, a2);
        a2 = fmaf(x2.z, y2.z, a2); a2 = fmaf(x2.w, y2.w, a2);
        a3 = fmaf(x3.x, y3.x, a3); a3 = fmaf(x3.y, y3.y, a3);
        a3 = fmaf(x3.z, y3.z, a3); a3 = fmaf(x3.w, y3.w, a3);
    }
    buf[t] = (a0 + a1) + (a2 + a3) + bias[q];
}

// ---------------------------------------------------------------------------
// level: for each parent node n in [start, start+count), each q:
//   new[q] = p[q] + maxl + maxr + log( sum_i el[i] * (sum_j ET[q][i][j]*er[j]) )
// thread = (parent, q). buf updated in place (p slot still holds sw here).
// ---------------------------------------------------------------------------
__global__ __launch_bounds__(256) void level_kernel(
    float* __restrict__ buf, const float* __restrict__ ETg,
    float* __restrict__ out, int start, int count)
{
    __shared__ float et[LC * ET_PAD];
    for (int idx = threadIdx.x; idx < LC * ET_PAD; idx += 256)
        et[idx] = ETg[idx];
    __syncthreads();

    int t  = blockIdx.x * 256 + threadIdx.x;
    int pj = t / 20;
    int q  = t - pj * 20;
    if (pj >= NB * count) return;
    int bi   = pj / count;
    int node = start + (pj - bi * count);
    size_t pbase = ((size_t)bi * NNODES + node) * LC;
    size_t lbase = ((size_t)bi * NNODES + 2 * node + 1) * LC;

    float l[20], r[20];
    const float4* l4 = (const float4*)(buf + lbase);
    const float4* r4 = (const float4*)(buf + lbase + LC);
    #pragma unroll
    for (int v = 0; v < 5; v++) {
        float4 lv = l4[v], rv = r4[v];
        l[4*v+0] = lv.x; l[4*v+1] = lv.y; l[4*v+2] = lv.z; l[4*v+3] = lv.w;
        r[4*v+0] = rv.x; r[4*v+1] = rv.y; r[4*v+2] = rv.z; r[4*v+3] = rv.w;
    }
    float maxl = l[0], maxr = r[0];
    #pragma unroll
    for (int i = 1; i < 20; i++) {
        maxl = fmaxf(maxl, l[i]);
        maxr = fmaxf(maxr, r[i]);
    }
    float el[20], er[20];
    #pragma unroll
    for (int i = 0; i < 20; i++) {
        el[i] = __expf(l[i] - maxl);
        er[i] = __expf(r[i] - maxr);
    }

    const float* etq = &et[q * ET_PAD];
    float s = 0.f;
    #pragma unroll
    for (int i = 0; i < 20; i++) {
        float d0 = 0.f, d1 = 0.f;
        #pragma unroll
        for (int j = 0; j < 20; j += 2) {
            d0 = fmaf(etq[i * 20 + j],     er[j],     d0);
            d1 = fmaf(etq[i * 20 + j + 1], er[j + 1], d1);
        }
        s = fmaf(el[i], d0 + d1, s);
    }

    float val = buf[pbase + q] + maxl + maxr + __logf(s);
    buf[pbase + q] = val;
    if (out) out[(size_t)bi * LC + q] = val;
}

// ---------------------------------------------------------------------------
extern "C" void kernel_launch(void* const* d_in, const int* in_sizes, int n_in,
                              void* d_out, int out_size, void* d_ws, size_t ws_size,
                              hipStream_t stream)
{
    const float* h     = (const float*)d_in[0];
    const float* W     = (const float*)d_in[1];
    const float* bias  = (const float*)d_in[2];
    const float* trans = (const float*)d_in[3];

    char* ws = (char*)d_ws;
    float* ET  = (float*)(ws);                                  // 20*404*4 = 32320 B
    float* Wt  = (float*)(ws + 32320);                          // 20*512*4 = 40960 B
    float* buf = (float*)(ws + 32320 + 40960);                  // 65472*20*4 = 5237760 B

    // 1. precompute exp(trans) reindexed + W^T
    prep_kernel<<<(LC * DIN + 255) / 256, 256, 0, stream>>>(trans, W, ET, Wt);

    // 2. sw = h@W + b for all 65472 rows
    {
        int T = NB * NNODES * LC;                 // 1,309,440
        gemm_kernel<<<(T + 255) / 256, 256, 0, stream>>>(h, Wt, bias, buf);
    }

    // 3. inside pass, level d = 8 .. 0
    for (int d = 8; d >= 0; --d) {
        int count = 1 << d;
        int start = count - 1;
        int T = NB * count * LC;
        int blocks = (T + 255) / 256;
        level_kernel<<<blocks, 256, 0, stream>>>(
            buf, ET, (d == 0) ? (float*)d_out : nullptr, start, count);
    }
}

// Round 2
// 109.041 us; speedup vs baseline: 3.8320x; 3.8320x over previous
//
#include <hip/hip_runtime.h>
#include <hip/hip_bf16.h>
#include <math.h>

#define NB      64      // batch
#define NNODES  1023    // 2*512-1
#define LC      20      // L*C = 5*4
#define DIN     512
#define NROWS   (NB * NNODES)   // 65472
#define ET_PAD  404     // 400 + 4 pad

#define TILE_R  128
#define KC      32
#define KPAD    36      // KC + 4: odd-ish stride in float4 units, aligned
#define NC      (DIN / KC)      // 16 chunks

// ---------------------------------------------------------------------------
// prep: ET[q][i*20+j] = exp(trans[lp,ll,lr,cp,cl,cr])
//   q = lp*4+cp, i = ll*4+cl, j = lr*4+cr
// ---------------------------------------------------------------------------
__global__ __launch_bounds__(256) void prep_kernel(
    const float* __restrict__ trans, float* __restrict__ ET)
{
    int t = blockIdx.x * 256 + threadIdx.x;
    if (t < 8000) {
        int q   = t % 20;
        int rem = t / 20;
        int j   = rem % 20;
        int i   = rem / 20;
        int ll = i >> 2, cl = i & 3;
        int lr = j >> 2, cr = j & 3;
        int lp = q >> 2, cp = q & 3;
        int src = ((((lp * 5 + ll) * 5 + lr) * 4 + cp) * 4 + cl) * 4 + cr;
        ET[q * ET_PAD + i * 20 + j] = expf(trans[src]);
    }
}

// ---------------------------------------------------------------------------
// gemm: buf[row][q] = dot(h[row,:], W[:,q]) + b[q]
// LDS-staged rows (double-buffered), B via wave-uniform scalar loads.
// ---------------------------------------------------------------------------
__global__ __launch_bounds__(128) void gemm_kernel(
    const float* __restrict__ h, const float* __restrict__ W,
    const float* __restrict__ bias, float* __restrict__ buf)
{
    __shared__ float As[2][TILE_R][KPAD];
    const int t    = threadIdx.x;
    const int row0 = blockIdx.x * TILE_R;
    const int row  = row0 + t;

    float acc[LC];
    #pragma unroll
    for (int q = 0; q < LC; ++q) acc[q] = 0.f;

    // stage chunk 0: 128 rows x 32 k  (idx -> rr = idx>>3, k4 = idx&7)
    #pragma unroll
    for (int i = 0; i < 8; ++i) {
        int idx = i * 128 + t;
        int rr = idx >> 3, k4 = idx & 7;
        int gr = row0 + rr;
        float4 v = make_float4(0.f, 0.f, 0.f, 0.f);
        if (gr < NROWS) v = *(const float4*)(h + (size_t)gr * DIN + k4 * 4);
        *(float4*)&As[0][rr][k4 * 4] = v;
    }
    __syncthreads();

    for (int c = 0; c < NC; ++c) {
        const int cur = c & 1;

        // issue next chunk's global loads early (hide HBM latency under FMAs)
        float4 nxt[8];
        if (c + 1 < NC) {
            const int k0n = (c + 1) * KC;
            #pragma unroll
            for (int i = 0; i < 8; ++i) {
                int idx = i * 128 + t;
                int rr = idx >> 3, k4 = idx & 7;
                int gr = row0 + rr;
                nxt[i] = make_float4(0.f, 0.f, 0.f, 0.f);
                if (gr < NROWS)
                    nxt[i] = *(const float4*)(h + (size_t)gr * DIN + k0n + k4 * 4);
            }
        }

        // compute on current chunk; B loads are wave-uniform -> s_load
        const int k0 = c * KC;
        #pragma unroll 4
        for (int k = 0; k < KC; ++k) {
            float a = As[cur][t][k];
            const float* Bk = W + (size_t)(k0 + k) * LC;
            #pragma unroll
            for (int q = 0; q < LC; ++q)
                acc[q] = fmaf(a, Bk[q], acc[q]);
        }

        // write next chunk into the other buffer; one barrier per iter
        if (c + 1 < NC) {
            #pragma unroll
            for (int i = 0; i < 8; ++i) {
                int idx = i * 128 + t;
                int rr = idx >> 3, k4 = idx & 7;
                *(float4*)&As[cur ^ 1][rr][k4 * 4] = nxt[i];
            }
        }
        __syncthreads();
    }

    if (row < NROWS) {
        float o[LC];
        #pragma unroll
        for (int q = 0; q < LC; ++q) o[q] = acc[q] + bias[q];
        float4* dst = (float4*)(buf + (size_t)row * LC);
        #pragma unroll
        for (int v = 0; v < 5; ++v)
            dst[v] = make_float4(o[4*v], o[4*v+1], o[4*v+2], o[4*v+3]);
    }
}

// ---------------------------------------------------------------------------
// level body (shared by level_kernel and tail_kernel)
// ---------------------------------------------------------------------------
__device__ __forceinline__ void level_body(
    float* __restrict__ buf, const float* __restrict__ et,
    float* __restrict__ out, int bi, int node, int q)
{
    size_t pbase = ((size_t)bi * NNODES + node) * LC;
    size_t lbase = ((size_t)bi * NNODES + 2 * node + 1) * LC;

    float l[LC], r[LC];
    const float4* l4 = (const float4*)(buf + lbase);
    const float4* r4 = (const float4*)(buf + lbase + LC);
    #pragma unroll
    for (int v = 0; v < 5; ++v) {
        float4 lv = l4[v], rv = r4[v];
        l[4*v+0] = lv.x; l[4*v+1] = lv.y; l[4*v+2] = lv.z; l[4*v+3] = lv.w;
        r[4*v+0] = rv.x; r[4*v+1] = rv.y; r[4*v+2] = rv.z; r[4*v+3] = rv.w;
    }
    float maxl = l[0], maxr = r[0];
    #pragma unroll
    for (int i = 1; i < LC; ++i) {
        maxl = fmaxf(maxl, l[i]);
        maxr = fmaxf(maxr, r[i]);
    }
    float el[LC], er[LC];
    #pragma unroll
    for (int i = 0; i < LC; ++i) {
        el[i] = __expf(l[i] - maxl);
        er[i] = __expf(r[i] - maxr);
    }

    const float4* etq = (const float4*)(et + q * ET_PAD);
    float s = 0.f;
    #pragma unroll
    for (int i = 0; i < LC; ++i) {
        float4 e0 = etq[i*5+0], e1 = etq[i*5+1], e2 = etq[i*5+2],
               e3 = etq[i*5+3], e4 = etq[i*5+4];
        float d0 = 0.f, d1 = 0.f;
        d0 = fmaf(e0.x, er[0],  d0); d1 = fmaf(e0.y, er[1],  d1);
        d0 = fmaf(e0.z, er[2],  d0); d1 = fmaf(e0.w, er[3],  d1);
        d0 = fmaf(e1.x, er[4],  d0); d1 = fmaf(e1.y, er[5],  d1);
        d0 = fmaf(e1.z, er[6],  d0); d1 = fmaf(e1.w, er[7],  d1);
        d0 = fmaf(e2.x, er[8],  d0); d1 = fmaf(e2.y, er[9],  d1);
        d0 = fmaf(e2.z, er[10], d0); d1 = fmaf(e2.w, er[11], d1);
        d0 = fmaf(e3.x, er[12], d0); d1 = fmaf(e3.y, er[13], d1);
        d0 = fmaf(e3.z, er[14], d0); d1 = fmaf(e3.w, er[15], d1);
        d0 = fmaf(e4.x, er[16], d0); d1 = fmaf(e4.y, er[17], d1);
        d0 = fmaf(e4.z, er[18], d0); d1 = fmaf(e4.w, er[19], d1);
        s = fmaf(el[i], d0 + d1, s);
    }

    float val = buf[pbase + q] + maxl + maxr + __logf(s);
    buf[pbase + q] = val;
    if (out) out[(size_t)bi * LC + q] = val;
}

// ---------------------------------------------------------------------------
// level: one launch per level for d = 8, 7, 6 (plenty of parallelism)
// ---------------------------------------------------------------------------
__global__ __launch_bounds__(256) void level_kernel(
    float* __restrict__ buf, const float* __restrict__ ETg,
    int start, int count)
{
    __shared__ float et[LC * ET_PAD];
    for (int idx = threadIdx.x; idx < LC * ET_PAD / 4; idx += 256)
        ((float4*)et)[idx] = ((const float4*)ETg)[idx];
    __syncthreads();

    int t  = blockIdx.x * 256 + threadIdx.x;
    int pj = t / LC;
    int q  = t - pj * LC;
    if (pj >= NB * count) return;
    int bi   = pj / count;
    int node = start + (pj - bi * count);
    level_body(buf, et, nullptr, bi, node, q);
}

// ---------------------------------------------------------------------------
// tail: levels d = 5..0 fused, one block per batch element
// ---------------------------------------------------------------------------
__global__ __launch_bounds__(640) void tail_kernel(
    float* __restrict__ buf, const float* __restrict__ ETg,
    float* __restrict__ out)
{
    __shared__ float et[LC * ET_PAD];
    for (int idx = threadIdx.x; idx < LC * ET_PAD / 4; idx += 640)
        ((float4*)et)[idx] = ((const float4*)ETg)[idx];
    __syncthreads();

    const int bi = blockIdx.x;
    for (int d = 5; d >= 0; --d) {
        int count = 1 << d;
        int start = count - 1;
        int t = threadIdx.x;
        if (t < count * LC) {
            int node = start + t / LC;
            int q    = t % LC;
            level_body(buf, et, (d == 0) ? out : nullptr, bi, node, q);
        }
        __syncthreads();
    }
}

// ---------------------------------------------------------------------------
extern "C" void kernel_launch(void* const* d_in, const int* in_sizes, int n_in,
                              void* d_out, int out_size, void* d_ws, size_t ws_size,
                              hipStream_t stream)
{
    const float* h     = (const float*)d_in[0];
    const float* W     = (const float*)d_in[1];
    const float* bias  = (const float*)d_in[2];
    const float* trans = (const float*)d_in[3];

    char* ws = (char*)d_ws;
    float* ET  = (float*)(ws);               // 20*404*4 = 32320 B (pad to 32768)
    float* buf = (float*)(ws + 32768);       // 65472*20*4 = 5237760 B

    // 1. precompute exp(trans) reindexed
    prep_kernel<<<(8000 + 255) / 256, 256, 0, stream>>>(trans, ET);

    // 2. sw = h@W + b
    gemm_kernel<<<(NROWS + TILE_R - 1) / TILE_R, TILE_R, 0, stream>>>(
        h, W, bias, buf);

    // 3. inside pass: big levels separate, small levels fused
    for (int d = 8; d >= 6; --d) {
        int count = 1 << d;
        int start = count - 1;
        int T = NB * count * LC;
        level_kernel<<<(T + 255) / 256, 256, 0, stream>>>(buf, ET, start, count);
    }
    tail_kernel<<<NB, 640, 0, stream>>>(buf, ET, (float*)d_out);
}

// Round 3
// 90.116 us; speedup vs baseline: 4.6367x; 1.2100x over previous
//
#include <hip/hip_runtime.h>
#include <hip/hip_bf16.h>
#include <math.h>

#define NB      64      // batch
#define NNODES  1023    // 2*512-1
#define LC      20      // L*C = 5*4
#define DIN     512
#define NROWS   (NB * NNODES)   // 65472 = 1023 * 64 exactly
#define ET_PAD  404     // 400 + 4 pad

#define TR      64              // rows per block
#define KC      32              // k per chunk
#define KPAD    33              // odd stride: As[lane][k] reads are conflict-free
#define NCH     (DIN / KC)      // 16 chunks

// ---------------------------------------------------------------------------
// prep: ET[q][i*20+j] = exp(trans[lp,ll,lr,cp,cl,cr])
//   q = lp*4+cp, i = ll*4+cl, j = lr*4+cr
// ---------------------------------------------------------------------------
__global__ __launch_bounds__(256) void prep_kernel(
    const float* __restrict__ trans, float* __restrict__ ET)
{
    int t = blockIdx.x * 256 + threadIdx.x;
    if (t < 8000) {
        int q   = t % 20;
        int rem = t / 20;
        int j   = rem % 20;
        int i   = rem / 20;
        int ll = i >> 2, cl = i & 3;
        int lr = j >> 2, cr = j & 3;
        int lp = q >> 2, cp = q & 3;
        int src = ((((lp * 5 + ll) * 5 + lr) * 4 + cp) * 4 + cl) * 4 + cr;
        ET[q * ET_PAD + i * 20 + j] = expf(trans[src]);
    }
}

// ---------------------------------------------------------------------------
// gemm: buf[row][q] = dot(h[row,:], W[:,q]) + b[q]
// 4 waves/block share one 64-row LDS tile; wave w computes q in [5w, 5w+5).
// W slice per (k, wave) is wave-uniform -> scalar loads (s_load broadcast).
// ---------------------------------------------------------------------------
__global__ __launch_bounds__(256) void gemm_kernel(
    const float* __restrict__ h, const float* __restrict__ W,
    const float* __restrict__ bias, float* __restrict__ buf)
{
    __shared__ float As[2][TR][KPAD];
    const int t    = threadIdx.x;
    const int lane = t & 63;
    const int w5   = __builtin_amdgcn_readfirstlane((t >> 6) * 5);
    const int row0 = blockIdx.x * TR;

    float acc[5] = {0.f, 0.f, 0.f, 0.f, 0.f};

    // stage chunk 0: 64 rows x 32 k = 512 float4, 2 per thread
    #pragma unroll
    for (int i = 0; i < 2; ++i) {
        int idx = i * 256 + t;
        int rr = idx >> 3, k4 = idx & 7;
        float4 v = *(const float4*)(h + (size_t)(row0 + rr) * DIN + k4 * 4);
        As[0][rr][k4 * 4 + 0] = v.x;
        As[0][rr][k4 * 4 + 1] = v.y;
        As[0][rr][k4 * 4 + 2] = v.z;
        As[0][rr][k4 * 4 + 3] = v.w;
    }
    __syncthreads();

    for (int c = 0; c < NCH; ++c) {
        const int cur = c & 1;

        // issue next chunk's global loads early
        float4 nxt[2];
        if (c + 1 < NCH) {
            const int k0n = (c + 1) * KC;
            #pragma unroll
            for (int i = 0; i < 2; ++i) {
                int idx = i * 256 + t;
                int rr = idx >> 3, k4 = idx & 7;
                nxt[i] = *(const float4*)(h + (size_t)(row0 + rr) * DIN + k0n + k4 * 4);
            }
        }

        // compute: per k, broadcast LDS row value, 5 scalar-W FMAs
        const int k0 = c * KC;
        #pragma unroll
        for (int k = 0; k < KC; ++k) {
            float a = As[cur][lane][k];
            const float* Wk = W + (size_t)(k0 + k) * LC + w5;
            acc[0] = fmaf(a, Wk[0], acc[0]);
            acc[1] = fmaf(a, Wk[1], acc[1]);
            acc[2] = fmaf(a, Wk[2], acc[2]);
            acc[3] = fmaf(a, Wk[3], acc[3]);
            acc[4] = fmaf(a, Wk[4], acc[4]);
        }

        // write next chunk into the other buffer
        if (c + 1 < NCH) {
            #pragma unroll
            for (int i = 0; i < 2; ++i) {
                int idx = i * 256 + t;
                int rr = idx >> 3, k4 = idx & 7;
                As[cur ^ 1][rr][k4 * 4 + 0] = nxt[i].x;
                As[cur ^ 1][rr][k4 * 4 + 1] = nxt[i].y;
                As[cur ^ 1][rr][k4 * 4 + 2] = nxt[i].z;
                As[cur ^ 1][rr][k4 * 4 + 3] = nxt[i].w;
            }
        }
        __syncthreads();
    }

    // epilogue: transpose through LDS (reuse As[0] region) -> coalesced float4
    float* as2 = &As[0][0][0];   // need 1280 floats, region holds 2112
    #pragma unroll
    for (int j = 0; j < 5; ++j)
        as2[lane * LC + w5 + j] = acc[j] + bias[w5 + j];
    __syncthreads();
    float4* dst = (float4*)(buf + (size_t)row0 * LC);
    const float4* src = (const float4*)as2;
    dst[t] = src[t];
    if (t < 64) dst[256 + t] = src[256 + t];
}

// ---------------------------------------------------------------------------
// level body (shared by level_kernel and tail_kernel)
// ---------------------------------------------------------------------------
__device__ __forceinline__ void level_body(
    float* __restrict__ buf, const float* __restrict__ et,
    float* __restrict__ out, int bi, int node, int q)
{
    size_t pbase = ((size_t)bi * NNODES + node) * LC;
    size_t lbase = ((size_t)bi * NNODES + 2 * node + 1) * LC;

    float l[LC], r[LC];
    const float4* l4 = (const float4*)(buf + lbase);
    const float4* r4 = (const float4*)(buf + lbase + LC);
    #pragma unroll
    for (int v = 0; v < 5; ++v) {
        float4 lv = l4[v], rv = r4[v];
        l[4*v+0] = lv.x; l[4*v+1] = lv.y; l[4*v+2] = lv.z; l[4*v+3] = lv.w;
        r[4*v+0] = rv.x; r[4*v+1] = rv.y; r[4*v+2] = rv.z; r[4*v+3] = rv.w;
    }
    float maxl = l[0], maxr = r[0];
    #pragma unroll
    for (int i = 1; i < LC; ++i) {
        maxl = fmaxf(maxl, l[i]);
        maxr = fmaxf(maxr, r[i]);
    }
    float el[LC], er[LC];
    #pragma unroll
    for (int i = 0; i < LC; ++i) {
        el[i] = __expf(l[i] - maxl);
        er[i] = __expf(r[i] - maxr);
    }

    const float4* etq = (const float4*)(et + q * ET_PAD);
    float s = 0.f;
    #pragma unroll
    for (int i = 0; i < LC; ++i) {
        float4 e0 = etq[i*5+0], e1 = etq[i*5+1], e2 = etq[i*5+2],
               e3 = etq[i*5+3], e4 = etq[i*5+4];
        float d0 = 0.f, d1 = 0.f;
        d0 = fmaf(e0.x, er[0],  d0); d1 = fmaf(e0.y, er[1],  d1);
        d0 = fmaf(e0.z, er[2],  d0); d1 = fmaf(e0.w, er[3],  d1);
        d0 = fmaf(e1.x, er[4],  d0); d1 = fmaf(e1.y, er[5],  d1);
        d0 = fmaf(e1.z, er[6],  d0); d1 = fmaf(e1.w, er[7],  d1);
        d0 = fmaf(e2.x, er[8],  d0); d1 = fmaf(e2.y, er[9],  d1);
        d0 = fmaf(e2.z, er[10], d0); d1 = fmaf(e2.w, er[11], d1);
        d0 = fmaf(e3.x, er[12], d0); d1 = fmaf(e3.y, er[13], d1);
        d0 = fmaf(e3.z, er[14], d0); d1 = fmaf(e3.w, er[15], d1);
        d0 = fmaf(e4.x, er[16], d0); d1 = fmaf(e4.y, er[17], d1);
        d0 = fmaf(e4.z, er[18], d0); d1 = fmaf(e4.w, er[19], d1);
        s = fmaf(el[i], d0 + d1, s);
    }

    float val = buf[pbase + q] + maxl + maxr + __logf(s);
    buf[pbase + q] = val;
    if (out) out[(size_t)bi * LC + q] = val;
}

// ---------------------------------------------------------------------------
// level: one launch per level for d = 8, 7, 6
// ---------------------------------------------------------------------------
__global__ __launch_bounds__(256) void level_kernel(
    float* __restrict__ buf, const float* __restrict__ ETg,
    int start, int count)
{
    __shared__ float et[LC * ET_PAD];
    for (int idx = threadIdx.x; idx < LC * ET_PAD / 4; idx += 256)
        ((float4*)et)[idx] = ((const float4*)ETg)[idx];
    __syncthreads();

    int t  = blockIdx.x * 256 + threadIdx.x;
    int pj = t / LC;
    int q  = t - pj * LC;
    if (pj >= NB * count) return;
    int bi   = pj / count;
    int node = start + (pj - bi * count);
    level_body(buf, et, nullptr, bi, node, q);
}

// ---------------------------------------------------------------------------
// tail: levels d = 5..0 fused, one block per batch element
// ---------------------------------------------------------------------------
__global__ __launch_bounds__(640) void tail_kernel(
    float* __restrict__ buf, const float* __restrict__ ETg,
    float* __restrict__ out)
{
    __shared__ float et[LC * ET_PAD];
    for (int idx = threadIdx.x; idx < LC * ET_PAD / 4; idx += 640)
        ((float4*)et)[idx] = ((const float4*)ETg)[idx];
    __syncthreads();

    const int bi = blockIdx.x;
    for (int d = 5; d >= 0; --d) {
        int count = 1 << d;
        int start = count - 1;
        int t = threadIdx.x;
        if (t < count * LC) {
            int node = start + t / LC;
            int q    = t % LC;
            level_body(buf, et, (d == 0) ? out : nullptr, bi, node, q);
        }
        __syncthreads();
    }
}

// ---------------------------------------------------------------------------
extern "C" void kernel_launch(void* const* d_in, const int* in_sizes, int n_in,
                              void* d_out, int out_size, void* d_ws, size_t ws_size,
                              hipStream_t stream)
{
    const float* h     = (const float*)d_in[0];
    const float* W     = (const float*)d_in[1];
    const float* bias  = (const float*)d_in[2];
    const float* trans = (const float*)d_in[3];

    char* ws = (char*)d_ws;
    float* ET  = (float*)(ws);               // 20*404*4 = 32320 B (pad to 32768)
    float* buf = (float*)(ws + 32768);       // 65472*20*4 = 5237760 B

    // 1. precompute exp(trans) reindexed
    prep_kernel<<<(8000 + 255) / 256, 256, 0, stream>>>(trans, ET);

    // 2. sw = h@W + b
    gemm_kernel<<<NROWS / TR, 256, 0, stream>>>(h, W, bias, buf);

    // 3. inside pass: big levels separate, small levels fused
    for (int d = 8; d >= 6; --d) {
        int count = 1 << d;
        int start = count - 1;
        int T = NB * count * LC;
        level_kernel<<<(T + 255) / 256, 256, 0, stream>>>(buf, ET, start, count);
    }
    tail_kernel<<<NB, 640, 0, stream>>>(buf, ET, (float*)d_out);
}